// Round 1
// baseline (170.899 us; speedup 1.0000x reference)
//
#include <hip/hip_runtime.h>
#include <stdint.h>

#define D_DIM 512
#define NSTEPS 10
#define ALPHA0 0.1f
#define DT_C 0.1f
#define BETA_C 2.8982753492378875f

typedef __attribute__((ext_vector_type(8))) short short8;
typedef __attribute__((ext_vector_type(4))) float floatx4;

__device__ __forceinline__ unsigned short f32_to_bf16(float f) {
    union { float f; uint32_t u; } v;
    v.f = f;
    uint32_t u = v.u;
    return (unsigned short)((u + 0x7FFFu + ((u >> 16) & 1u)) >> 16);
}

// ---------------------------------------------------------------------------
// Kernel 1: build L_rw in bf16 (row-major [e][d]) and init chain state
//   At0 = I (f32, transposed storage At[c][e]=A[e][c]; I is symmetric)
//   Bt0 = 0, Abf0 = bf16(I)
// ---------------------------------------------------------------------------
__global__ __launch_bounds__(256) void prep_kernel(
    const float* __restrict__ W,
    unsigned short* __restrict__ Lbf,
    float* __restrict__ At0, float* __restrict__ Bt0,
    unsigned short* __restrict__ Abf0)
{
    const int e = blockIdx.x;
    const int tid = threadIdx.x;
    __shared__ float red[4];
    float s = 0.f;
    for (int d = tid; d < D_DIM; d += 256) s += fabsf(W[e * D_DIM + d]);
#pragma unroll
    for (int off = 32; off > 0; off >>= 1) s += __shfl_down(s, off, 64);
    if ((tid & 63) == 0) red[tid >> 6] = s;
    __syncthreads();
    float deg = red[0] + red[1] + red[2] + red[3];
    deg = fmaxf(deg, 1e-8f);
    const float inv = 1.0f / deg;
    for (int d = tid; d < D_DIM; d += 256) {
        const float diag = (d == e) ? 1.0f : 0.0f;
        const float lv = diag - fabsf(W[e * D_DIM + d]) * inv;
        Lbf[e * D_DIM + d] = f32_to_bf16(lv);
        At0[e * D_DIM + d] = diag;
        Bt0[e * D_DIM + d] = 0.0f;
        Abf0[e * D_DIM + d] = (d == e) ? (unsigned short)0x3F80 : (unsigned short)0;
    }
}

// ---------------------------------------------------------------------------
// Kernel 2: one settling step on the 512x512 operator matrices.
//   Ct[c][e] = sum_d At[c][d] * L[e][d]      (MFMA: A-op = Abf row-major,
//                                             B-op^T = Lbf row-major)
//   force = -Ct - a0*At - prec[e]*At + prec[e]*(e==c) - beta*Bt
//   Bt' = Bt + dt*force ; At' = At + dt*Bt'
// Tile 64x64, 4 waves (2x2), each wave 32x32 = 2x2 MFMA frags.
// ---------------------------------------------------------------------------
__global__ __launch_bounds__(256) void step_kernel(
    const unsigned short* __restrict__ Lbf,   // [e][d]
    const unsigned short* __restrict__ Abf,   // [c][d]
    const float* __restrict__ At,
    const float* __restrict__ Bt,
    const float* __restrict__ prec,
    float* __restrict__ At_n,
    float* __restrict__ Bt_n,
    unsigned short* __restrict__ Abf_n)
{
    const int tid = threadIdx.x;
    const int wave = tid >> 6, lane = tid & 63;
    const int wr = wave >> 1, wc = wave & 1;
    const int c_base = blockIdx.y * 64 + wr * 32;
    const int e_base = blockIdx.x * 64 + wc * 32;
    const int lrow = lane & 15;
    const int lk = (lane >> 4) * 8;

    floatx4 acc[2][2] = {};
    for (int k0 = 0; k0 < D_DIM; k0 += 32) {
        short8 a[2], b[2];
#pragma unroll
        for (int m = 0; m < 2; ++m)
            a[m] = *(const short8*)(Abf + (size_t)(c_base + m * 16 + lrow) * D_DIM + k0 + lk);
#pragma unroll
        for (int n = 0; n < 2; ++n)
            b[n] = *(const short8*)(Lbf + (size_t)(e_base + n * 16 + lrow) * D_DIM + k0 + lk);
#pragma unroll
        for (int m = 0; m < 2; ++m)
#pragma unroll
            for (int n = 0; n < 2; ++n)
                acc[m][n] = __builtin_amdgcn_mfma_f32_16x16x32_bf16(a[m], b[n], acc[m][n], 0, 0, 0);
    }

#pragma unroll
    for (int m = 0; m < 2; ++m) {
#pragma unroll
        for (int n = 0; n < 2; ++n) {
            const int e_idx = e_base + n * 16 + lrow;
            const float pe = prec[e_idx];
#pragma unroll
            for (int j = 0; j < 4; ++j) {
                const int c_idx = c_base + m * 16 + (lane >> 4) * 4 + j;
                const size_t idx = (size_t)c_idx * D_DIM + e_idx;
                const float Av = At[idx];
                const float Bv = Bt[idx];
                const float tgt = (e_idx == c_idx) ? 1.0f : 0.0f;
                const float force = -acc[m][n][j] - ALPHA0 * Av + pe * (tgt - Av) - BETA_C * Bv;
                const float Bn2 = Bv + DT_C * force;
                const float An2 = Av + DT_C * Bn2;
                At_n[idx] = An2;
                Bt_n[idx] = Bn2;
                Abf_n[idx] = f32_to_bf16(An2);
            }
        }
    }
}

// ---------------------------------------------------------------------------
// Kernel 3: G[e][d] = (1-g)*delta_ed + g*A10[e][d],  A10[e][d] = At10[d][e].
// Diagonal pulled out to fp32 Gdiag; Gbf stores off-diagonal only (diag=0).
// ---------------------------------------------------------------------------
__global__ __launch_bounds__(256) void gbuild_kernel(
    const float* __restrict__ At10,
    const float* __restrict__ gate_alpha,
    unsigned short* __restrict__ Gbf,   // [e][d]
    float* __restrict__ Gdiag)
{
    const int idx = blockIdx.x * 256 + threadIdx.x;
    const int e = idx >> 9, d = idx & 511;
    const float g = tanhf(gate_alpha[0]);
    float val = g * At10[(size_t)d * D_DIM + e];
    if (d == e) {
        Gdiag[e] = (1.0f - g) + val;
        val = 0.0f;
    }
    Gbf[idx] = f32_to_bf16(val);
}

// ---------------------------------------------------------------------------
// Kernel 4: out = H @ G^T.  out[r][e] = H[r][e]*Gdiag[e] + sum_d H[r][d]*Goff[e][d]
// Tile M=64 rows x N=512 (full), 8 waves; wave w owns cols [w*64, w*64+64).
// H tile staged in LDS as bf16, XOR-swizzled; B-frags direct from L2 (Gbf).
// ---------------------------------------------------------------------------
__global__ __launch_bounds__(512) void out_gemm(
    const float* __restrict__ H,              // [16384][512]
    const unsigned short* __restrict__ Gbf,   // [e][d]
    const float* __restrict__ Gdiag,
    float* __restrict__ Out)
{
    const int r0 = blockIdx.x * 64;
    const int tid = threadIdx.x;
    const int wave = tid >> 6, lane = tid & 63;

    __shared__ unsigned short hlds[64 * D_DIM];  // 64 KiB, swizzled rows

    // stage: wave w loads rows {w, 8+w, ...}; lanes cover 512 cols, 8 each
#pragma unroll
    for (int i = 0; i < 8; ++i) {
        const int row = i * 8 + wave;
        const float* src = H + (size_t)(r0 + row) * D_DIM + lane * 8;
        const float4 v0 = *(const float4*)src;
        const float4 v1 = *(const float4*)(src + 4);
        short8 pk;
        pk[0] = (short)f32_to_bf16(v0.x); pk[1] = (short)f32_to_bf16(v0.y);
        pk[2] = (short)f32_to_bf16(v0.z); pk[3] = (short)f32_to_bf16(v0.w);
        pk[4] = (short)f32_to_bf16(v1.x); pk[5] = (short)f32_to_bf16(v1.y);
        pk[6] = (short)f32_to_bf16(v1.z); pk[7] = (short)f32_to_bf16(v1.w);
        int byte = row * (D_DIM * 2) + lane * 16;
        byte ^= (row & 7) << 4;
        *(short8*)((char*)hlds + byte) = pk;
    }
    __syncthreads();

    const int lrow = lane & 15;
    const int lkq = lane >> 4;

    floatx4 acc[4][4] = {};
    for (int k0 = 0; k0 < D_DIM; k0 += 32) {
        short8 a[4], b[4];
#pragma unroll
        for (int m = 0; m < 4; ++m) {
            const int row = m * 16 + lrow;
            int byte = row * (D_DIM * 2) + (k0 + lkq * 8) * 2;
            byte ^= (row & 7) << 4;
            a[m] = *(const short8*)((const char*)hlds + byte);
        }
#pragma unroll
        for (int n = 0; n < 4; ++n) {
            const int e = wave * 64 + n * 16 + lrow;
            b[n] = *(const short8*)(Gbf + (size_t)e * D_DIM + k0 + lkq * 8);
        }
#pragma unroll
        for (int m = 0; m < 4; ++m)
#pragma unroll
            for (int n = 0; n < 4; ++n)
                acc[m][n] = __builtin_amdgcn_mfma_f32_16x16x32_bf16(a[m], b[n], acc[m][n], 0, 0, 0);
    }

#pragma unroll
    for (int m = 0; m < 4; ++m) {
#pragma unroll
        for (int n = 0; n < 4; ++n) {
            const int e = wave * 64 + n * 16 + lrow;
            const float gd = Gdiag[e];
#pragma unroll
            for (int j = 0; j < 4; ++j) {
                const int r = r0 + m * 16 + lkq * 4 + j;
                const size_t idx = (size_t)r * D_DIM + e;
                Out[idx] = acc[m][n][j] + H[idx] * gd;
            }
        }
    }
}

// ---------------------------------------------------------------------------
extern "C" void kernel_launch(void* const* d_in, const int* in_sizes, int n_in,
                              void* d_out, int out_size, void* d_ws, size_t ws_size,
                              hipStream_t stream)
{
    const float* H    = (const float*)d_in[0];   // (4,4096,512)
    const float* W    = (const float*)d_in[1];   // (512,512)
    const float* gate = (const float*)d_in[2];   // (1,)
    const float* prec = (const float*)d_in[3];   // (512,)
    float* out = (float*)d_out;
    char* ws = (char*)d_ws;

    // ws layout (bytes): all regions 1 KiB aligned, ~6 MiB total
    unsigned short* Lbf    = (unsigned short*)(ws + (0u << 10));
    unsigned short* Abf0   = (unsigned short*)(ws + (512u << 10));
    unsigned short* Abf1   = (unsigned short*)(ws + (1024u << 10));
    unsigned short* Gbf    = (unsigned short*)(ws + (1536u << 10));
    float*          At0    = (float*)(ws + (2048u << 10));
    float*          At1    = (float*)(ws + (3072u << 10));
    float*          Bt0    = (float*)(ws + (4096u << 10));
    float*          Bt1    = (float*)(ws + (5120u << 10));
    float*          Gdiag  = (float*)(ws + (6144u << 10));

    unsigned short* Abf[2] = {Abf0, Abf1};
    float* At[2] = {At0, At1};
    float* Bt[2] = {Bt0, Bt1};

    prep_kernel<<<dim3(D_DIM), dim3(256), 0, stream>>>(W, Lbf, At[0], Bt[0], Abf[0]);

    for (int s = 0; s < NSTEPS; ++s) {
        const int src = s & 1, dst = src ^ 1;
        step_kernel<<<dim3(8, 8), dim3(256), 0, stream>>>(
            Lbf, Abf[src], At[src], Bt[src], prec, At[dst], Bt[dst], Abf[dst]);
    }
    // NSTEPS=10 (even) -> final state in index 0

    gbuild_kernel<<<dim3((D_DIM * D_DIM) / 256), dim3(256), 0, stream>>>(
        At[0], gate, Gbf, Gdiag);

    out_gemm<<<dim3(16384 / 64), dim3(512), 0, stream>>>(H, Gbf, Gdiag, out);
}